// Round 15
// baseline (1027.848 us; speedup 1.0000x reference)
//
#include <hip/hip_runtime.h>
#include <hip/hip_bf16.h>

// MoE top-2-of-8 FFN + shared expert + router losses, MI355X gfx950.
// R8: m97-canonical 128^2 single-buffer GEMM, 4 blocks/CU.
// R15: ev+sk backfill merge, ONE code path (233us; pigeonhole floor ~210).
// R17/R18: dispatch-count and sv-shape changes neutral -> gaps ~0; remaining
//     serial waste = the two transpose walls (~36us each) + router half-idle.
// R19: backfill the transposes (R15 merge pattern; R14 LDS-union trap avoided
//     by aliasing ONE shared buffer):
//     - keys+sk transpose (9216 tiny blocks) merged into router dispatch
//       (independent data; router's 512x25us items first, tr backfills).
//     - values+sv transpose merged into ek's tail; values now write a
//       SEPARATE wtV buffer (ek still reading wtK) -> +75.5MB ws.
//       Shared mem union: one 32KB char buf (tile aliases As) -> LDS 32768,
//       4 blocks/CU preserved. 10 -> 8 dispatches, ~72us serial -> backfill.
//     ev_sk / sv / scatter / scan / init_cvt byte-identical controls.

#define N_TOK 8192
#define DM    1024
#define HD    4096
#define NE    8
#define NKTOT 16384            // N_TOK * 2
#define PERM_CAP 17408         // NKTOT + NE*128 (segment padding)
#define MAX_TILES 136          // sum ceil(T_e/128) <= NKTOT/128 + NE
#define BAND 17                // MAX_TILES / 8 xcds
#define EV_BLOCKS 1088         // 8 xcd * 17 m * 8 n
#define EK_BLOCKS 5120         // 8 xcd * 20(m pad) * 32 n
#define RTR_BLOCKS 512         // router blocks
#define TR_BLOCKS 9216         // 9-slice 64x64-tile transpose blocks
#define RTOK_BLK 16            // router tokens per block

typedef __attribute__((ext_vector_type(8))) short bhalf8;
typedef __attribute__((ext_vector_type(8))) unsigned short ushort8v;
typedef __attribute__((ext_vector_type(4))) float floatx4;

__device__ __forceinline__ unsigned short f2bf(float f) {
  union { float f; unsigned int u; } v; v.f = f;
  unsigned int u = v.u;
  return (unsigned short)((u + 0x7fffu + ((u >> 16) & 1u)) >> 16);  // RNE
}

__device__ __forceinline__ float bf2f(unsigned short h) {
  union { unsigned int u; float f; } v; v.u = ((unsigned int)h) << 16;
  return v.f;
}

__device__ __forceinline__ float gelu_tanh(float h) {
  // jax.nn.gelu default (approximate=True)
  float u = 0.7978845608028654f * (h + 0.044715f * h * h * h);
  float t = 1.0f - 2.0f / (1.0f + __expf(2.0f * u));   // tanh(u)
  return 0.5f * h * (1.0f + t);
}

// global -> LDS direct DMA, 16B/lane. LDS dest is wave-uniform base + lane*16.
__device__ __forceinline__ void gload16(const unsigned short* g, void* l) {
  __builtin_amdgcn_global_load_lds(
      (const __attribute__((address_space(1))) void*)g,
      (__attribute__((address_space(3))) void*)l, 16, 0, 0);
}

// transpose 64x64 tile: src fp32 [R][C] block (r0=bx*64, c0=by*64) -> dst bf16 [C][R]
__device__ __forceinline__ void tr_body_p(float (*tile)[65],
                                          const float* __restrict__ src,
                                          unsigned short* __restrict__ dst,
                                          int R, int C, int bx, int by) {
  int r0 = bx * 64, c0 = by * 64;
  int c = threadIdx.x & 63, r = threadIdx.x >> 6;
#pragma unroll
  for (int i = 0; i < 16; i++)
    tile[r + i * 4][c] = src[(size_t)(r0 + r + i * 4) * C + c0 + c];
  __syncthreads();
  int u = threadIdx.x & 7;        // dst 8-col group (src row group)
  int ow = threadIdx.x >> 3;      // 0..31: dst row offset base
#pragma unroll
  for (int it = 0; it < 2; it++) {
    int oc = ow + it * 32;        // src col -> dst row offset
    ushort8v o;
#pragma unroll
    for (int j = 0; j < 8; j++) o[j] = f2bf(tile[u * 8 + j][oc]);
    *(ushort8v*)&dst[(size_t)(c0 + oc) * R + r0 + u * 8] = o;
  }
}

// ---------------- init (poisoned ws) + x fp32->bf16, one dispatch ----------------
__global__ void init_cvt_kernel(const float* __restrict__ x, unsigned short* __restrict__ xb,
                                int* perm, float* permw, float* usage, float* zsum,
                                int* counts, int* fill) {
  int i = blockIdx.x * 256 + threadIdx.x;
  size_t ci = (size_t)i * 4;
  float4 v = *(const float4*)(x + ci);
  ushort4 o;
  o.x = f2bf(v.x); o.y = f2bf(v.y); o.z = f2bf(v.z); o.w = f2bf(v.w);
  *(ushort4*)(xb + ci) = o;
  if (i < PERM_CAP) { perm[i] = 0; permw[i] = 0.0f; }
  if (i < NE) { usage[i] = 0.0f; counts[i] = 0; fill[i] = 0; }
  if (i == 0) zsum[0] = 0.0f;
}

// ---------------- merged router + keys/sk transpose ----------------
// ids [0,512) = router (25us items, first); ids [512,9728) = keys 9-slice
// transpose backfill (keys_w slices 0..7 -> wtK, sk_w -> wtK slot 8).
// Independent data; LDS = tile(16.6KB) + router arrays (sum, fine).
__global__ void router_keystr_kernel(
    const float* __restrict__ x, const float* __restrict__ gw,
    int* __restrict__ idxb, float* __restrict__ wbuf,
    float* __restrict__ usage, float* __restrict__ zsum, int* __restrict__ counts,
    const float* __restrict__ keys_w, const float* __restrict__ sk_w,
    unsigned short* __restrict__ wtK) {
  __shared__ float tile[64][65];
  __shared__ float s_use[NE];
  __shared__ int   s_cnt[NE];
  __shared__ float s_z;

  int id = blockIdx.x;
  int t = threadIdx.x;
  if (id >= RTR_BLOCKS) {                 // ---- transpose branch ----
    int tt = id - RTR_BLOCKS;             // keys grid was (16, 64, 9)
    int bx = tt & 15, by = (tt >> 4) & 63, z = tt >> 10;
    const float* src = (z < NE) ? keys_w + (size_t)z * DM * HD : sk_w;
    unsigned short* dst = wtK + (size_t)z * DM * HD;
    tr_body_p(tile, src, dst, DM, HD, bx, by);
    return;
  }

  // ---- router branch (verbatim R17) ----
  if (t < NE) { s_use[t] = 0.0f; s_cnt[t] = 0; }
  if (t == 0) s_z = 0.0f;
  __syncthreads();

  int wave = t >> 6;
  int lane = t & 63;

  float luse[NE]; int lcnt[NE];
#pragma unroll
  for (int e = 0; e < NE; e++) { luse[e] = 0.0f; lcnt[e] = 0; }
  float lz = 0.0f;

#pragma unroll
  for (int i = 0; i < 4; i++) {
    int n = id * RTOK_BLK + wave * 4 + i;
    const float* xr = x + (size_t)n * DM;
    float acc[NE];
#pragma unroll
    for (int e = 0; e < NE; e++) acc[e] = 0.0f;
    for (int d = lane; d < DM; d += 64) {
      float xv = xr[d];
      const float* g = gw + (size_t)d * NE;
#pragma unroll
      for (int e = 0; e < NE; e++) acc[e] += xv * g[e];
    }
#pragma unroll
    for (int e = 0; e < NE; e++) {
#pragma unroll
      for (int off = 32; off > 0; off >>= 1) acc[e] += __shfl_xor(acc[e], off);
    }
    if (lane == 0) {
      float m1 = acc[0]; int i1 = 0;
#pragma unroll
      for (int e = 1; e < NE; e++) if (acc[e] > m1) { m1 = acc[e]; i1 = e; }
      float m2 = -3.0e38f; int i2 = 0;
#pragma unroll
      for (int e = 0; e < NE; e++) if (e != i1 && acc[e] > m2) { m2 = acc[e]; i2 = e; }
      float e1 = __expf(m2 - m1);
      float w1 = 1.0f / (1.0f + e1);
      float w2 = e1 / (1.0f + e1);
      float s = 0.0f;
#pragma unroll
      for (int e = 0; e < NE; e++) s += __expf(acc[e] - m1);
      float lse = m1 + __logf(s);
      idxb[n * 2 + 0] = i1; idxb[n * 2 + 1] = i2;
      wbuf[n * 2 + 0] = w1; wbuf[n * 2 + 1] = w2;
      luse[i1] += w1; luse[i2] += w2;
      lcnt[i1]++;     lcnt[i2]++;
      lz += lse * lse;
    }
  }

  if (lane == 0) {
#pragma unroll
    for (int e = 0; e < NE; e++) {
      atomicAdd(&s_use[e], luse[e]);
      atomicAdd(&s_cnt[e], lcnt[e]);
    }
    atomicAdd(&s_z, lz);
  }
  __syncthreads();
  if (t < NE) {
    atomicAdd(&usage[t], s_use[t]);
    atomicAdd(&counts[t], s_cnt[t]);
  }
  if (t == 0) atomicAdd(zsum, s_z);
}

// ---------------- scan: padded segment offsets, tile table, router loss ----------------
__global__ void scan_kernel(const int* __restrict__ counts, int* __restrict__ poff,
                            int* __restrict__ tileE, int* __restrict__ tileR,
                            int* __restrict__ nTiles,
                            const float* __restrict__ usage, const float* __restrict__ zsum,
                            float* __restrict__ lossOut) {
  if (threadIdx.x == 0 && blockIdx.x == 0) {
    int run = 0, nt = 0;
    for (int e = 0; e < NE; e++) {
      poff[e] = run;
      int t = (counts[e] + 127) >> 7;
      for (int i = 0; i < t; i++) { tileE[nt] = e; tileR[nt] = run + i * 128; nt++; }
      run += t << 7;
    }
    *nTiles = nt;
    float mean = 0.0f;
    for (int e = 0; e < NE; e++) mean += usage[e];
    mean *= (1.0f / NE);
    float var = 0.0f;
    for (int e = 0; e < NE; e++) { float d = usage[e] - mean; var += d * d; }
    var *= (1.0f / NE);
    float bal = sqrtf(var) / mean * 0.01f;
    float z = (zsum[0] / (float)N_TOK) * 0.001f;
    lossOut[0] = bal + z;
  }
}

// ---------------- scatter tokens into per-expert segments ----------------
__global__ void scatter_kernel(const int* __restrict__ idxb, const float* __restrict__ wbuf,
                               const int* __restrict__ poff, int* __restrict__ fill,
                               int* __restrict__ perm, float* __restrict__ permw,
                               int* __restrict__ pos) {
  __shared__ int lcnt[NE];
  __shared__ int lbase[NE];
  int t = threadIdx.x;
  if (t < NE) lcnt[t] = 0;
  __syncthreads();
  int i = blockIdx.x * 256 + t;          // grid sized exactly: i < NKTOT
  int e = idxb[i];
  int r = atomicAdd(&lcnt[e], 1);        // LDS rank within block
  __syncthreads();
  if (t < NE) lbase[t] = atomicAdd(&fill[t], lcnt[t]);
  __syncthreads();
  int p = poff[e] + lbase[e] + r;
  perm[p] = i >> 1;
  permw[p] = wbuf[i];
  pos[i] = p;
}

// ---------------- combine: out[t] += eout[pos0[t]] + eout[pos1[t]] ----------------
__global__ void combine_kernel(float* __restrict__ out,
                               const unsigned short* __restrict__ eout,
                               const int* __restrict__ pos) {
  int t = blockIdx.x;
  int d = threadIdx.x * 8;
  int p0 = pos[t * 2], p1 = pos[t * 2 + 1];
  float* o = out + (size_t)t * DM + d;
  const unsigned short* e0 = eout + (size_t)p0 * DM + d;
  const unsigned short* e1 = eout + (size_t)p1 * DM + d;
  float4 a = *(const float4*)(o);
  float4 b = *(const float4*)(o + 4);
  ushort4 u0a = *(const ushort4*)(e0), u0b = *(const ushort4*)(e0 + 4);
  ushort4 u1a = *(const ushort4*)(e1), u1b = *(const ushort4*)(e1 + 4);
  a.x += bf2f(u0a.x) + bf2f(u1a.x);
  a.y += bf2f(u0a.y) + bf2f(u1a.y);
  a.z += bf2f(u0a.z) + bf2f(u1a.z);
  a.w += bf2f(u0a.w) + bf2f(u1a.w);
  b.x += bf2f(u0b.x) + bf2f(u1b.x);
  b.y += bf2f(u0b.y) + bf2f(u1b.y);
  b.z += bf2f(u0b.z) + bf2f(u1b.z);
  b.w += bf2f(u0b.w) + bf2f(u1b.w);
  *(float4*)(o) = a;
  *(float4*)(o + 4) = b;
}

// ---------------- merged expert-keys + values/sv transpose ----------------
// ids [0,5120) = ek items (26us, first; 4352 active);
// ids [5120,14336) = values 9-slice transpose backfill -> SEPARATE wtV buffer
// (ek concurrently reads wtK). One 32KB shared buffer: ek uses As/Bs halves,
// transpose aliases the tile (16.6KB) over it -> LDS stays 32768, 4 blocks/CU.
__global__ __launch_bounds__(256, 4) void gemm_ek_vtr(
    const unsigned short* __restrict__ A, const unsigned short* __restrict__ wtK,
    const float* __restrict__ bias, unsigned short* __restrict__ outH,
    const int* __restrict__ perm, const int* __restrict__ tileE,
    const int* __restrict__ tileR, const int* __restrict__ nTiles,
    const float* __restrict__ values_w, const float* __restrict__ sv_w,
    unsigned short* __restrict__ wtV) {
  __shared__ __align__(16) char shbuf[32768];
  unsigned short* As = (unsigned short*)shbuf;
  unsigned short* Bs = (unsigned short*)(shbuf + 16384);

  int id = blockIdx.x;
  if (id >= EK_BLOCKS) {                  // ---- transpose branch ----
    int tt = id - EK_BLOCKS;              // values grid was (64, 16, 9)
    int bx = tt & 63, by = (tt >> 6) & 15, z = tt >> 10;
    const float* src = (z < NE) ? values_w + (size_t)z * HD * DM : sv_w;
    unsigned short* dst = wtV + (size_t)z * HD * DM;
    tr_body_p((float(*)[65])shbuf, src, dst, HD, DM, bx, by);
    return;
  }

  // ---- ek branch (verbatim R17/18 body) ----
  int xcd = id & 7, q = id >> 3;
  int n_in = q & 7, m_in = (q >> 3) & 3, ng = (q >> 5) & 3, mg = q >> 7;
  int mband = mg * 4 + m_in;
  if (mband >= BAND) return;
  int mt = xcd * BAND + mband;
  int ntile = ng * 8 + n_in;
  if (mt >= *nTiles) return;
  int e = tileE[mt];
  int prow0 = tileR[mt];
  const unsigned short* BT = wtK + (size_t)e * DM * HD;
  const float* be = bias + (size_t)e * HD;
  int n0 = ntile * 128;

  int t = threadIdx.x;
  int rsub = t >> 3;
  int gc = (t & 7) ^ (rsub & 7);
  const unsigned short* aptr[4];
  const unsigned short* bptr[4];
#pragma unroll
  for (int p = 0; p < 4; p++) {
    int r = rsub + p * 32;
    aptr[p] = A + (size_t)perm[prow0 + r] * DM + gc * 8;
    bptr[p] = BT + (size_t)(n0 + r) * DM + gc * 8;
  }
  char* ldsA = shbuf + (t & 192) * 16;
  char* ldsB = shbuf + 16384 + (t & 192) * 16;

  int lane = t & 63;
  int wv = t >> 6;
  int wm = (wv >> 1) * 64, wn = (wv & 1) * 64;
  int lr = lane & 15, lq = lane >> 4;
  int rx = lr & 7;

  floatx4 acc[4][4];
#pragma unroll
  for (int i = 0; i < 4; i++)
#pragma unroll
    for (int j = 0; j < 4; j++) acc[i][j] = (floatx4){0.f, 0.f, 0.f, 0.f};

  for (int k0 = 0; k0 < DM; k0 += 64) {
#pragma unroll
    for (int p = 0; p < 4; p++) {
      gload16(aptr[p] + k0, ldsA + p * 4096);
      gload16(bptr[p] + k0, ldsB + p * 4096);
    }
    __syncthreads();
#pragma unroll
    for (int kk = 0; kk < 2; kk++) {
      int ca = kk * 4 + lq;
      bhalf8 af[4], bf[4];
#pragma unroll
      for (int i = 0; i < 4; i++) {
        af[i] = *(const bhalf8*)&As[(wm + i * 16 + lr) * 64 + ((ca ^ rx) * 8)];
        bf[i] = *(const bhalf8*)&Bs[(wn + i * 16 + lr) * 64 + ((ca ^ rx) * 8)];
      }
#pragma unroll
      for (int mtile = 0; mtile < 4; mtile++)
#pragma unroll
        for (int ntl = 0; ntl < 4; ntl++)
          acc[mtile][ntl] = __builtin_amdgcn_mfma_f32_16x16x32_bf16(af[mtile], bf[ntl], acc[mtile][ntl], 0, 0, 0);
    }
    __syncthreads();
  }

#pragma unroll
  for (int mtile = 0; mtile < 4; mtile++) {
#pragma unroll
    for (int ntl = 0; ntl < 4; ntl++) {
      int ncol = n0 + wn + ntl * 16 + lr;
      float bb = be[ncol];
#pragma unroll
      for (int r = 0; r < 4; r++) {
        int mrow = wm + mtile * 16 + lq * 4 + r;
        float v = acc[mtile][ntl][r] + bb;
        outH[(size_t)(prow0 + mrow) * HD + ncol] = f2bf(gelu_tanh(v));
      }
    }
  }
}

// ---------------- shared values: 128x64 body, 1024 blocks exact ----------------
__global__ __launch_bounds__(256, 4) void gemm_shared_values(
    const unsigned short* __restrict__ A, const unsigned short* __restrict__ BT,
    const float* __restrict__ bias, float* __restrict__ outF) {
  __shared__ __align__(16) unsigned short As[128 * 64];   // 16 KB
  __shared__ __align__(16) unsigned short Bs[64 * 64];    // 8 KB

  int id = blockIdx.x;
  int xcd = id & 7, q = id >> 3;          // q 0..127
  int mt = xcd * 8 + (q >> 4);            // 64 m-tiles
  int ntile = q & 15;                     // 16 n-tiles of 64
  int m0 = mt * 128, n0 = ntile * 64;

  int t = threadIdx.x;
  int rsub = t >> 3;
  int gc = (t & 7) ^ (rsub & 7);
  const unsigned short* aptr[4];
  const unsigned short* bptr[2];
#pragma unroll
  for (int p = 0; p < 4; p++)
    aptr[p] = A + (size_t)(m0 + rsub + p * 32) * HD + gc * 8;
#pragma unroll
  for (int p = 0; p < 2; p++)
    bptr[p] = BT + (size_t)(n0 + rsub + p * 32) * HD + gc * 8;
  char* ldsA = (char*)As + (t & 192) * 16;
  char* ldsB = (char*)Bs + (t & 192) * 16;

  int lane = t & 63;
  int wv = t >> 6;
  int wm = (wv >> 1) * 64, wn = (wv & 1) * 32;    // wave tile 64m x 32n
  int lr = lane & 15, lq = lane >> 4;
  int rx = lr & 7;

  floatx4 acc[4][2];
#pragma unroll
  for (int i = 0; i < 4; i++)
#pragma unroll
    for (int j = 0; j < 2; j++) acc[i][j] = (floatx4){0.f, 0.f, 0.f, 0.f};

  for (int k0 = 0; k0 < HD; k0 += 64) {
#pragma unroll
    for (int p = 0; p < 4; p++) gload16(aptr[p] + k0, ldsA + p * 4096);
#pragma unroll
    for (int p = 0; p < 2; p++) gload16(bptr[p] + k0, ldsB + p * 4096);
    __syncthreads();
#pragma unroll
    for (int kk = 0; kk < 2; kk++) {
      int ca = kk * 4 + lq;
      bhalf8 af[4], bf[2];
#pragma unroll
      for (int i = 0; i < 4; i++)
        af[i] = *(const bhalf8*)&As[(wm + i * 16 + lr) * 64 + ((ca ^ rx) * 8)];
#pragma unroll
      for (int j = 0; j < 2; j++)
        bf[j] = *(const bhalf8*)&Bs[(wn + j * 16 + lr) * 64 + ((ca ^ rx) * 8)];
#pragma unroll
      for (int i = 0; i < 4; i++)
#pragma unroll
        for (int j = 0; j < 2; j++)
          acc[i][j] = __builtin_amdgcn_mfma_f32_16x16x32_bf16(af[i], bf[j], acc[i][j], 0, 0, 0);
    }
    __syncthreads();
  }

#pragma unroll
  for (int i = 0; i < 4; i++) {
#pragma unroll
    for (int j = 0; j < 2; j++) {
      int ncol = n0 + wn + j * 16 + lr;
      float bb = bias[ncol];
#pragma unroll
      for (int r = 0; r < 4; r++) {
        int mrow = m0 + wm + i * 16 + lq * 4 + r;
        outF[(size_t)mrow * DM + ncol] = acc[i][j][r] + bb;
      }
    }
  }
}

// ---------------- merged ev+sk: ONE code path (R15-verified) ----------------
__global__ __launch_bounds__(256, 4) void gemm_ev_sk(
    const unsigned short* __restrict__ hid, const unsigned short* __restrict__ wtV,
    const float* __restrict__ values_b, unsigned short* __restrict__ eout,
    const unsigned short* __restrict__ xb, const unsigned short* __restrict__ wtK8,
    const float* __restrict__ sk_b, unsigned short* __restrict__ hidS,
    const float* __restrict__ permw,
    const int* __restrict__ tileE, const int* __restrict__ tileR,
    const int* __restrict__ nTiles) {
  __shared__ __align__(16) unsigned short As[128 * 64];
  __shared__ __align__(16) unsigned short Bs[128 * 64];

  int id = blockIdx.x;
  bool is_ev = id < EV_BLOCKS;

  int Kd, rbase, n0;
  const unsigned short* A;
  const unsigned short* BT;
  const float* bias;
  if (is_ev) {                       // band 17m, n-fastest per m
    int xcd = id & 7, q = id >> 3;
    int mt = xcd * BAND + (q >> 3);
    if (mt >= *nTiles) return;
    int e = tileE[mt];
    rbase = tileR[mt];
    n0 = (q & 7) * 128;
    Kd = HD;
    A = hid;
    BT = wtV + (size_t)e * HD * DM;
    bias = values_b + (size_t)e * DM;
  } else {                           // sk: band 8m, m-fastest
    int id2 = id - EV_BLOCKS;
    int xcd = id2 & 7, q = id2 >> 3;
    int mt = xcd * 8 + (q & 7);
    rbase = mt * 128;
    n0 = (q >> 3) * 128;
    Kd = DM;
    A = xb;
    BT = wtK8;
    bias = sk_b;
  }

  int t = threadIdx.x;
  int rsub = t >> 3;
  int gc = (t & 7) ^ (rsub & 7);
  const unsigned short* aptr[4];
  const unsigned short* bptr[4];
#pragma unroll
  for (int p = 0; p < 4; p++) {
    int r = rsub + p * 32;
    aptr[p] = A + (size_t)(rbase + r) * Kd + gc * 8;
    bptr[p] = BT + (size_t)(n0 + r) * Kd + gc * 8;
  }
  char* ldsA = (char*)As + (t & 192) * 16;
  char* ldsB = (char*)Bs + (t & 192) * 16;

  int lane = t & 63;
  int wv = t >> 6;
  int wm = (wv >> 1) * 64, wn = (wv & 1) * 64;
  int lr = lane & 15, lq = lane >> 4;
  int rx = lr & 7;

  floatx4 acc[4][4];
#pragma unroll
  for (int i = 0; i < 4; i++)
#pragma unroll
    for (int j = 0; j < 4; j++) acc[i][j] = (floatx4){0.f, 0.f, 0.f, 0.f};

  for (int k0 = 0; k0 < Kd; k0 += 64) {
#pragma unroll
    for (int p = 0; p < 4; p++) {
      gload16(aptr[p] + k0, ldsA + p * 4096);
      gload16(bptr[p] + k0, ldsB + p * 4096);
    }
    __syncthreads();
#pragma unroll
    for (int kk = 0; kk < 2; kk++) {
      int ca = kk * 4 + lq;
      bhalf8 af[4], bf[4];
#pragma unroll
      for (int i = 0; i < 4; i++) {
        af[i] = *(const bhalf8*)&As[(wm + i * 16 + lr) * 64 + ((ca ^ rx) * 8)];
        bf[i] = *(const bhalf8*)&Bs[(wn + i * 16 + lr) * 64 + ((ca ^ rx) * 8)];
      }
#pragma unroll
      for (int mtile = 0; mtile < 4; mtile++)
#pragma unroll
        for (int ntl = 0; ntl < 4; ntl++)
          acc[mtile][ntl] = __builtin_amdgcn_mfma_f32_16x16x32_bf16(af[mtile], bf[ntl], acc[mtile][ntl], 0, 0, 0);
    }
    __syncthreads();
  }

  if (is_ev) {
#pragma unroll
    for (int mtile = 0; mtile < 4; mtile++) {
#pragma unroll
      for (int ntl = 0; ntl < 4; ntl++) {
        int ncol = n0 + wn + ntl * 16 + lr;
        float bb = bias[ncol];
#pragma unroll
        for (int r = 0; r < 4; r++) {
          int prow = rbase + wm + mtile * 16 + lq * 4 + r;
          float w = permw[prow];
          float v = acc[mtile][ntl][r] + bb;
          eout[(size_t)prow * DM + ncol] = f2bf(w * v);
        }
      }
    }
  } else {
#pragma unroll
    for (int mtile = 0; mtile < 4; mtile++) {
#pragma unroll
      for (int ntl = 0; ntl < 4; ntl++) {
        int ncol = n0 + wn + ntl * 16 + lr;
        float bb = bias[ncol];
#pragma unroll
        for (int r = 0; r < 4; r++) {
          int mrow = rbase + wm + mtile * 16 + lq * 4 + r;
          float v = acc[mtile][ntl][r] + bb;
          hidS[(size_t)mrow * HD + ncol] = f2bf(gelu_tanh(v));
        }
      }
    }
  }
}

extern "C" void kernel_launch(void* const* d_in, const int* in_sizes, int n_in,
                              void* d_out, int out_size, void* d_ws, size_t ws_size,
                              hipStream_t stream) {
  const float* x        = (const float*)d_in[0];
  const float* gate_w   = (const float*)d_in[1];
  const float* keys_w   = (const float*)d_in[2];
  const float* keys_b   = (const float*)d_in[3];
  const float* values_w = (const float*)d_in[4];
  const float* values_b = (const float*)d_in[5];
  const float* sk_w     = (const float*)d_in[6];
  const float* sk_b     = (const float*)d_in[7];
  const float* sv_w     = (const float*)d_in[8];
  const float* sv_b     = (const float*)d_in[9];
  float* out = (float*)d_out;

  char* p = (char*)d_ws;
  unsigned short* xb   = (unsigned short*)p; p += (size_t)N_TOK * DM * 2;              // 16 MB
  unsigned short* wtK  = (unsigned short*)p; p += (size_t)(NE + 1) * DM * HD * 2;      // 75.5 MB (keys 0..7 + sk)
  unsigned short* wtV  = (unsigned short*)p; p += (size_t)(NE + 1) * DM * HD * 2;      // 75.5 MB (values 0..7 + sv)
  unsigned short* hid  = (unsigned short*)p; p += (size_t)(PERM_CAP + N_TOK) * HD * 2; // 209.7 MB
  unsigned short* eout = (unsigned short*)p; p += (size_t)PERM_CAP * DM * 2;           // 35.7 MB
  int*   idxb   = (int*)p;   p += NKTOT * 4;
  float* wbuf   = (float*)p; p += NKTOT * 4;
  int*   perm   = (int*)p;   p += PERM_CAP * 4;
  float* permw  = (float*)p; p += PERM_CAP * 4;
  int*   pos    = (int*)p;   p += NKTOT * 4;
  int*   counts = (int*)p;   p += NE * 4;
  int*   fill   = (int*)p;   p += NE * 4;
  int*   poff   = (int*)p;   p += NE * 4;
  float* usage  = (float*)p; p += NE * 4;
  float* zsum   = (float*)p; p += 16;
  int*   tileE  = (int*)p;   p += MAX_TILES * 4;
  int*   tileR  = (int*)p;   p += MAX_TILES * 4;
  int*   nTiles = (int*)p;   p += 16;

  float* lossOut = out + (size_t)N_TOK * DM;
  unsigned short* wtK8 = wtK + (size_t)NE * DM * HD;           // sk_w^T slot
  unsigned short* wtV8 = wtV + (size_t)NE * DM * HD;           // sv_w^T slot
  unsigned short* hidS = hid + (size_t)PERM_CAP * HD;          // shared hidden rows

  // 1) init+cvt; then router with keys/sk-transpose backfill
  init_cvt_kernel<<<N_TOK * DM / 4 / 256, 256, 0, stream>>>(
      x, xb, perm, permw, usage, zsum, counts, fill);
  router_keystr_kernel<<<RTR_BLOCKS + TR_BLOCKS, 256, 0, stream>>>(
      x, gate_w, idxb, wbuf, usage, zsum, counts, keys_w, sk_w, wtK);
  scan_kernel<<<1, 64, 0, stream>>>(counts, poff, tileE, tileR, nTiles, usage, zsum, lossOut);
  scatter_kernel<<<NKTOT / 256, 256, 0, stream>>>(idxb, wbuf, poff, fill, perm, permw, pos);

  // 2) expert keys with values/sv-transpose backfill (tr writes separate wtV)
  gemm_ek_vtr<<<EK_BLOCKS + TR_BLOCKS, 256, 0, stream>>>(
      xb, wtK, keys_b, hid, perm, tileE, tileR, nTiles, values_w, sv_w, wtV);

  // 3) merged ev+sk (reads wtV + wtK8)
  gemm_ev_sk<<<EV_BLOCKS + 2048, 256, 0, stream>>>(
      hid, wtV, values_b, eout, xb, wtK8, sk_b, hidS,
      permw, tileE, tileR, nTiles);

  // 4) shared values (reads wtV8), then combine
  gemm_shared_values<<<1024, 256, 0, stream>>>(hidS, wtV8, sv_b, out);
  combine_kernel<<<N_TOK, 128, 0, stream>>>(out, eout, pos);
}

// Round 16
// 943.564 us; speedup vs baseline: 1.0893x; 1.0893x over previous
//
#include <hip/hip_runtime.h>
#include <hip/hip_bf16.h>

// MoE top-2-of-8 FFN + shared expert + router losses, MI355X gfx950.
// R8: m97-canonical 128^2 single-buffer GEMM, 4 blocks/CU.
// R15: ev+sk backfill merge, ONE code path (233us). Best ~887us.
// R16/R19 post-mortem: co-scheduling streaming transposes with the ek
//     gather-GEMM destroys ek's L2 weight reuse (FETCH 580MB, WRITE 794MB,
//     1.4GB @ 3.4TB/s = pure HBM wall). REVERTED; transposes stay serial.
// R20: ev_sk pigeonhole fix. 1088 x 105us ev items on 1024 slots forces a
//     2-item slot (makespan >= 210; measured 233). Shrink items: BOTH
//     branches BN=64 (R11/R18-verified 128x64 body, same per-CU rate):
//     ev -> 2176 x ~53us, sk -> 4096 x ~13us; busy 168.5k slot-us / 1024
//     = 164.5 ideal, bound ~159 -> expect ~175-200. ONE uniform code path
//     (acc[4][2]=32 AGPR, LDS 24KB, runtime operands) avoids the R14
//     LDS/VGPR-union trap. Everything else byte-identical to R18.

#define N_TOK 8192
#define DM    1024
#define HD    4096
#define NE    8
#define NKTOT 16384            // N_TOK * 2
#define PERM_CAP 17408         // NKTOT + NE*128 (segment padding)
#define MAX_TILES 136          // sum ceil(T_e/128) <= NKTOT/128 + NE
#define BAND 17                // MAX_TILES / 8 xcds
#define EV2_BLOCKS 2176        // 8 xcd * 17 m * 16 n (BN=64)
#define SK2_BLOCKS 4096        // 8 xcd * 8 m * 64 n (BN=64)
#define RTOK_BLK 16            // router tokens per block

typedef __attribute__((ext_vector_type(8))) short bhalf8;
typedef __attribute__((ext_vector_type(8))) unsigned short ushort8v;
typedef __attribute__((ext_vector_type(4))) float floatx4;

__device__ __forceinline__ unsigned short f2bf(float f) {
  union { float f; unsigned int u; } v; v.f = f;
  unsigned int u = v.u;
  return (unsigned short)((u + 0x7fffu + ((u >> 16) & 1u)) >> 16);  // RNE
}

__device__ __forceinline__ float bf2f(unsigned short h) {
  union { unsigned int u; float f; } v; v.u = ((unsigned int)h) << 16;
  return v.f;
}

__device__ __forceinline__ float gelu_tanh(float h) {
  // jax.nn.gelu default (approximate=True)
  float u = 0.7978845608028654f * (h + 0.044715f * h * h * h);
  float t = 1.0f - 2.0f / (1.0f + __expf(2.0f * u));   // tanh(u)
  return 0.5f * h * (1.0f + t);
}

// global -> LDS direct DMA, 16B/lane. LDS dest is wave-uniform base + lane*16.
__device__ __forceinline__ void gload16(const unsigned short* g, void* l) {
  __builtin_amdgcn_global_load_lds(
      (const __attribute__((address_space(1))) void*)g,
      (__attribute__((address_space(3))) void*)l, 16, 0, 0);
}

// ---------------- init (poisoned ws) + x fp32->bf16, one dispatch ----------------
__global__ void init_cvt_kernel(const float* __restrict__ x, unsigned short* __restrict__ xb,
                                int* perm, float* permw, float* usage, float* zsum,
                                int* counts, int* fill) {
  int i = blockIdx.x * 256 + threadIdx.x;
  size_t ci = (size_t)i * 4;
  float4 v = *(const float4*)(x + ci);
  ushort4 o;
  o.x = f2bf(v.x); o.y = f2bf(v.y); o.z = f2bf(v.z); o.w = f2bf(v.w);
  *(ushort4*)(xb + ci) = o;
  if (i < PERM_CAP) { perm[i] = 0; permw[i] = 0.0f; }
  if (i < NE) { usage[i] = 0.0f; counts[i] = 0; fill[i] = 0; }
  if (i == 0) zsum[0] = 0.0f;
}

// ---------------- router: logits, top-2 softmax, aux-loss partials ----------------
__global__ void router_kernel(const float* __restrict__ x, const float* __restrict__ gw,
                              int* __restrict__ idxb, float* __restrict__ wbuf,
                              float* __restrict__ usage, float* __restrict__ zsum,
                              int* __restrict__ counts) {
  __shared__ float s_use[NE];
  __shared__ int   s_cnt[NE];
  __shared__ float s_z;
  int t = threadIdx.x;
  if (t < NE) { s_use[t] = 0.0f; s_cnt[t] = 0; }
  if (t == 0) s_z = 0.0f;
  __syncthreads();

  int wave = t >> 6;
  int lane = t & 63;

  float luse[NE]; int lcnt[NE];
#pragma unroll
  for (int e = 0; e < NE; e++) { luse[e] = 0.0f; lcnt[e] = 0; }
  float lz = 0.0f;

#pragma unroll
  for (int i = 0; i < 4; i++) {
    int n = blockIdx.x * RTOK_BLK + wave * 4 + i;
    const float* xr = x + (size_t)n * DM;
    float acc[NE];
#pragma unroll
    for (int e = 0; e < NE; e++) acc[e] = 0.0f;
    for (int d = lane; d < DM; d += 64) {
      float xv = xr[d];
      const float* g = gw + (size_t)d * NE;
#pragma unroll
      for (int e = 0; e < NE; e++) acc[e] += xv * g[e];
    }
#pragma unroll
    for (int e = 0; e < NE; e++) {
#pragma unroll
      for (int off = 32; off > 0; off >>= 1) acc[e] += __shfl_xor(acc[e], off);
    }
    if (lane == 0) {
      float m1 = acc[0]; int i1 = 0;
#pragma unroll
      for (int e = 1; e < NE; e++) if (acc[e] > m1) { m1 = acc[e]; i1 = e; }
      float m2 = -3.0e38f; int i2 = 0;
#pragma unroll
      for (int e = 0; e < NE; e++) if (e != i1 && acc[e] > m2) { m2 = acc[e]; i2 = e; }
      float e1 = __expf(m2 - m1);
      float w1 = 1.0f / (1.0f + e1);
      float w2 = e1 / (1.0f + e1);
      float s = 0.0f;
#pragma unroll
      for (int e = 0; e < NE; e++) s += __expf(acc[e] - m1);
      float lse = m1 + __logf(s);
      idxb[n * 2 + 0] = i1; idxb[n * 2 + 1] = i2;
      wbuf[n * 2 + 0] = w1; wbuf[n * 2 + 1] = w2;
      luse[i1] += w1; luse[i2] += w2;
      lcnt[i1]++;     lcnt[i2]++;
      lz += lse * lse;
    }
  }

  if (lane == 0) {
#pragma unroll
    for (int e = 0; e < NE; e++) {
      atomicAdd(&s_use[e], luse[e]);
      atomicAdd(&s_cnt[e], lcnt[e]);
    }
    atomicAdd(&s_z, lz);
  }
  __syncthreads();
  if (t < NE) {
    atomicAdd(&usage[t], s_use[t]);
    atomicAdd(&counts[t], s_cnt[t]);
  }
  if (t == 0) atomicAdd(zsum, s_z);
}

// ---------------- scan: padded segment offsets, tile table, router loss ----------------
__global__ void scan_kernel(const int* __restrict__ counts, int* __restrict__ poff,
                            int* __restrict__ tileE, int* __restrict__ tileR,
                            int* __restrict__ nTiles,
                            const float* __restrict__ usage, const float* __restrict__ zsum,
                            float* __restrict__ lossOut) {
  if (threadIdx.x == 0 && blockIdx.x == 0) {
    int run = 0, nt = 0;
    for (int e = 0; e < NE; e++) {
      poff[e] = run;
      int t = (counts[e] + 127) >> 7;
      for (int i = 0; i < t; i++) { tileE[nt] = e; tileR[nt] = run + i * 128; nt++; }
      run += t << 7;
    }
    *nTiles = nt;
    float mean = 0.0f;
    for (int e = 0; e < NE; e++) mean += usage[e];
    mean *= (1.0f / NE);
    float var = 0.0f;
    for (int e = 0; e < NE; e++) { float d = usage[e] - mean; var += d * d; }
    var *= (1.0f / NE);
    float bal = sqrtf(var) / mean * 0.01f;
    float z = (zsum[0] / (float)N_TOK) * 0.001f;
    lossOut[0] = bal + z;
  }
}

// ---------------- scatter tokens into per-expert segments ----------------
__global__ void scatter_kernel(const int* __restrict__ idxb, const float* __restrict__ wbuf,
                               const int* __restrict__ poff, int* __restrict__ fill,
                               int* __restrict__ perm, float* __restrict__ permw,
                               int* __restrict__ pos) {
  __shared__ int lcnt[NE];
  __shared__ int lbase[NE];
  int t = threadIdx.x;
  if (t < NE) lcnt[t] = 0;
  __syncthreads();
  int i = blockIdx.x * 256 + t;          // grid sized exactly: i < NKTOT
  int e = idxb[i];
  int r = atomicAdd(&lcnt[e], 1);        // LDS rank within block
  __syncthreads();
  if (t < NE) lbase[t] = atomicAdd(&fill[t], lcnt[t]);
  __syncthreads();
  int p = poff[e] + lbase[e] + r;
  perm[p] = i >> 1;
  permw[p] = wbuf[i];
  pos[i] = p;
}

// ---------------- transpose+convert: fp32 [R][C] -> bf16 [C][R] ----------------
__device__ __forceinline__ void tr_body(const float* __restrict__ src,
                                        unsigned short* __restrict__ dst, int R, int C) {
  __shared__ float tile[64][65];
  int r0 = blockIdx.x * 64, c0 = blockIdx.y * 64;
  int c = threadIdx.x & 63, r = threadIdx.x >> 6;
#pragma unroll
  for (int i = 0; i < 16; i++)
    tile[r + i * 4][c] = src[(size_t)(r0 + r + i * 4) * C + c0 + c];
  __syncthreads();
  int u = threadIdx.x & 7;        // dst 8-col group (src row group)
  int ow = threadIdx.x >> 3;      // 0..31: dst row offset base
#pragma unroll
  for (int it = 0; it < 2; it++) {
    int oc = ow + it * 32;        // src col -> dst row offset
    ushort8v o;
#pragma unroll
    for (int j = 0; j < 8; j++) o[j] = f2bf(tile[u * 8 + j][oc]);
    *(ushort8v*)&dst[(size_t)(c0 + oc) * R + r0 + u * 8] = o;
  }
}

// 9-slice: z<8 -> srcB slice z -> dstB slice z; z==8 -> src1 -> dst1.
__global__ void transpose_cvt9_kernel(const float* __restrict__ srcB,
                                      const float* __restrict__ src1,
                                      unsigned short* __restrict__ dstB,
                                      unsigned short* __restrict__ dst1, int R, int C) {
  int z = blockIdx.z;
  const float* src = (z < NE) ? srcB + (size_t)z * R * C : src1;
  unsigned short* dst = (z < NE) ? dstB + (size_t)z * R * C : dst1;
  tr_body(src, dst, R, C);
}

// ---------------- combine: out[t] += eout[pos0[t]] + eout[pos1[t]] ----------------
__global__ void combine_kernel(float* __restrict__ out,
                               const unsigned short* __restrict__ eout,
                               const int* __restrict__ pos) {
  int t = blockIdx.x;
  int d = threadIdx.x * 8;
  int p0 = pos[t * 2], p1 = pos[t * 2 + 1];
  float* o = out + (size_t)t * DM + d;
  const unsigned short* e0 = eout + (size_t)p0 * DM + d;
  const unsigned short* e1 = eout + (size_t)p1 * DM + d;
  float4 a = *(const float4*)(o);
  float4 b = *(const float4*)(o + 4);
  ushort4 u0a = *(const ushort4*)(e0), u0b = *(const ushort4*)(e0 + 4);
  ushort4 u1a = *(const ushort4*)(e1), u1b = *(const ushort4*)(e1 + 4);
  a.x += bf2f(u0a.x) + bf2f(u1a.x);
  a.y += bf2f(u0a.y) + bf2f(u1a.y);
  a.z += bf2f(u0a.z) + bf2f(u1a.z);
  a.w += bf2f(u0a.w) + bf2f(u1a.w);
  b.x += bf2f(u0b.x) + bf2f(u1b.x);
  b.y += bf2f(u0b.y) + bf2f(u1b.y);
  b.z += bf2f(u0b.z) + bf2f(u1b.z);
  b.w += bf2f(u0b.w) + bf2f(u1b.w);
  *(float4*)(o) = a;
  *(float4*)(o + 4) = b;
}

// ---------------- expert keys: 128x128 body, perm rows, gelu bf16 out ----------------
__global__ __launch_bounds__(256, 4) void gemm_expert_keys(
    const unsigned short* __restrict__ A, const unsigned short* __restrict__ BT,
    const float* __restrict__ bias, unsigned short* __restrict__ outH,
    int Kd, int Nd,
    const int* __restrict__ perm, const int* __restrict__ tileE,
    const int* __restrict__ tileR, const int* __restrict__ nTiles) {
  __shared__ __align__(16) unsigned short As[128 * 64];
  __shared__ __align__(16) unsigned short Bs[128 * 64];

  int id = blockIdx.x;
  int xcd = id & 7, q = id >> 3;
  int n_in = q & 7, m_in = (q >> 3) & 3, ng = (q >> 5) & 3, mg = q >> 7;
  int mband = mg * 4 + m_in;
  if (mband >= BAND) return;
  int mt = xcd * BAND + mband;
  int ntile = ng * 8 + n_in;
  if (mt >= *nTiles) return;
  int e = tileE[mt];
  int prow0 = tileR[mt];
  BT += (size_t)e * Kd * Nd;
  bias += (size_t)e * Nd;
  int n0 = ntile * 128;

  int t = threadIdx.x;
  int rsub = t >> 3;
  int gc = (t & 7) ^ (rsub & 7);
  const unsigned short* aptr[4];
  const unsigned short* bptr[4];
#pragma unroll
  for (int p = 0; p < 4; p++) {
    int r = rsub + p * 32;
    aptr[p] = A + (size_t)perm[prow0 + r] * Kd + gc * 8;
    bptr[p] = BT + (size_t)(n0 + r) * Kd + gc * 8;
  }
  char* ldsA = (char*)As + (t & 192) * 16;
  char* ldsB = (char*)Bs + (t & 192) * 16;

  int lane = t & 63;
  int wv = t >> 6;
  int wm = (wv >> 1) * 64, wn = (wv & 1) * 64;
  int lr = lane & 15, lq = lane >> 4;
  int rx = lr & 7;

  floatx4 acc[4][4];
#pragma unroll
  for (int i = 0; i < 4; i++)
#pragma unroll
    for (int j = 0; j < 4; j++) acc[i][j] = (floatx4){0.f, 0.f, 0.f, 0.f};

  for (int k0 = 0; k0 < Kd; k0 += 64) {
#pragma unroll
    for (int p = 0; p < 4; p++) {
      gload16(aptr[p] + k0, ldsA + p * 4096);
      gload16(bptr[p] + k0, ldsB + p * 4096);
    }
    __syncthreads();
#pragma unroll
    for (int kk = 0; kk < 2; kk++) {
      int ca = kk * 4 + lq;
      bhalf8 af[4], bf[4];
#pragma unroll
      for (int i = 0; i < 4; i++) {
        af[i] = *(const bhalf8*)&As[(wm + i * 16 + lr) * 64 + ((ca ^ rx) * 8)];
        bf[i] = *(const bhalf8*)&Bs[(wn + i * 16 + lr) * 64 + ((ca ^ rx) * 8)];
      }
#pragma unroll
      for (int mtile = 0; mtile < 4; mtile++)
#pragma unroll
        for (int ntl = 0; ntl < 4; ntl++)
          acc[mtile][ntl] = __builtin_amdgcn_mfma_f32_16x16x32_bf16(af[mtile], bf[ntl], acc[mtile][ntl], 0, 0, 0);
    }
    __syncthreads();
  }

#pragma unroll
  for (int mtile = 0; mtile < 4; mtile++) {
#pragma unroll
    for (int ntl = 0; ntl < 4; ntl++) {
      int ncol = n0 + wn + ntl * 16 + lr;
      float bb = bias[ncol];
#pragma unroll
      for (int r = 0; r < 4; r++) {
        int mrow = wm + mtile * 16 + lq * 4 + r;
        float v = acc[mtile][ntl][r] + bb;
        outH[(size_t)(prow0 + mrow) * Nd + ncol] = f2bf(gelu_tanh(v));
      }
    }
  }
}

// ---------------- shared values: 128x64 body, 1024 blocks exact ----------------
__global__ __launch_bounds__(256, 4) void gemm_shared_values(
    const unsigned short* __restrict__ A, const unsigned short* __restrict__ BT,
    const float* __restrict__ bias, float* __restrict__ outF) {
  __shared__ __align__(16) unsigned short As[128 * 64];   // 16 KB
  __shared__ __align__(16) unsigned short Bs[64 * 64];    // 8 KB

  int id = blockIdx.x;
  int xcd = id & 7, q = id >> 3;          // q 0..127
  int mt = xcd * 8 + (q >> 4);            // 64 m-tiles
  int ntile = q & 15;                     // 16 n-tiles of 64
  int m0 = mt * 128, n0 = ntile * 64;

  int t = threadIdx.x;
  int rsub = t >> 3;
  int gc = (t & 7) ^ (rsub & 7);
  const unsigned short* aptr[4];
  const unsigned short* bptr[2];
#pragma unroll
  for (int p = 0; p < 4; p++)
    aptr[p] = A + (size_t)(m0 + rsub + p * 32) * HD + gc * 8;
#pragma unroll
  for (int p = 0; p < 2; p++)
    bptr[p] = BT + (size_t)(n0 + rsub + p * 32) * HD + gc * 8;
  char* ldsA = (char*)As + (t & 192) * 16;
  char* ldsB = (char*)Bs + (t & 192) * 16;

  int lane = t & 63;
  int wv = t >> 6;
  int wm = (wv >> 1) * 64, wn = (wv & 1) * 32;    // wave tile 64m x 32n
  int lr = lane & 15, lq = lane >> 4;
  int rx = lr & 7;

  floatx4 acc[4][2];
#pragma unroll
  for (int i = 0; i < 4; i++)
#pragma unroll
    for (int j = 0; j < 2; j++) acc[i][j] = (floatx4){0.f, 0.f, 0.f, 0.f};

  for (int k0 = 0; k0 < HD; k0 += 64) {
#pragma unroll
    for (int p = 0; p < 4; p++) gload16(aptr[p] + k0, ldsA + p * 4096);
#pragma unroll
    for (int p = 0; p < 2; p++) gload16(bptr[p] + k0, ldsB + p * 4096);
    __syncthreads();
#pragma unroll
    for (int kk = 0; kk < 2; kk++) {
      int ca = kk * 4 + lq;
      bhalf8 af[4], bf[2];
#pragma unroll
      for (int i = 0; i < 4; i++)
        af[i] = *(const bhalf8*)&As[(wm + i * 16 + lr) * 64 + ((ca ^ rx) * 8)];
#pragma unroll
      for (int j = 0; j < 2; j++)
        bf[j] = *(const bhalf8*)&Bs[(wn + j * 16 + lr) * 64 + ((ca ^ rx) * 8)];
#pragma unroll
      for (int i = 0; i < 4; i++)
#pragma unroll
        for (int j = 0; j < 2; j++)
          acc[i][j] = __builtin_amdgcn_mfma_f32_16x16x32_bf16(af[i], bf[j], acc[i][j], 0, 0, 0);
    }
    __syncthreads();
  }

#pragma unroll
  for (int i = 0; i < 4; i++) {
#pragma unroll
    for (int j = 0; j < 2; j++) {
      int ncol = n0 + wn + j * 16 + lr;
      float bb = bias[ncol];
#pragma unroll
      for (int r = 0; r < 4; r++) {
        int mrow = m0 + wm + i * 16 + lq * 4 + r;
        outF[(size_t)mrow * DM + ncol] = acc[i][j][r] + bb;
      }
    }
  }
}

// ---------------- merged ev+sk, BN=64 uniform body ----------------
// ids [0,2176) = expert_values (K=4096, ~53us items, first);
// ids [2176,6272) = shared_keys (K=1024, ~13us items, backfill).
// ONE code path: 128x64 tile, acc[4][2]=32 AGPR, LDS 24KB. Pigeonhole bound
// drops from 2x105=210 to 3x53=159; busy 168.5k slot-us / 1024 = 164.5 ideal.
__global__ __launch_bounds__(256, 4) void gemm_ev_sk(
    const unsigned short* __restrict__ hid, const unsigned short* __restrict__ wtV,
    const float* __restrict__ values_b, unsigned short* __restrict__ eout,
    const unsigned short* __restrict__ xb, const unsigned short* __restrict__ wtK8,
    const float* __restrict__ sk_b, unsigned short* __restrict__ hidS,
    const float* __restrict__ permw,
    const int* __restrict__ tileE, const int* __restrict__ tileR,
    const int* __restrict__ nTiles) {
  __shared__ __align__(16) unsigned short As[128 * 64];   // 16 KB
  __shared__ __align__(16) unsigned short Bs[64 * 64];    // 8 KB

  int id = blockIdx.x;
  bool is_ev = id < EV2_BLOCKS;

  int Kd, Nd, rbase, n0;
  const unsigned short* A;
  const unsigned short* BT;
  const float* bias;
  if (is_ev) {                       // 8 xcd * 17 m * 16 n; n-fastest per m
    int xcd = id & 7, q = id >> 3;   // q 0..271
    int mt = xcd * BAND + (q >> 4);
    if (mt >= *nTiles) return;
    int e = tileE[mt];
    rbase = tileR[mt];
    n0 = (q & 15) * 64;
    Kd = HD; Nd = DM;
    A = hid;
    BT = wtV + (size_t)e * HD * DM;
    bias = values_b + (size_t)e * DM;
  } else {                           // sk: 8 xcd * 8 m * 64 n
    int id2 = id - EV2_BLOCKS;
    int xcd = id2 & 7, q = id2 >> 3; // q 0..511
    int mt = xcd * 8 + (q & 7);
    rbase = mt * 128;
    n0 = (q >> 3) * 64;
    Kd = DM; Nd = HD;
    A = xb;
    BT = wtK8;
    bias = sk_b;
  }

  int t = threadIdx.x;
  int rsub = t >> 3;               // 0..31: row within 32-row staging slab
  int gc = (t & 7) ^ (rsub & 7);   // swizzled global 16B-chunk index
  const unsigned short* aptr[4];
  const unsigned short* bptr[2];
#pragma unroll
  for (int p = 0; p < 4; p++)
    aptr[p] = A + (size_t)(rbase + rsub + p * 32) * Kd + gc * 8;
#pragma unroll
  for (int p = 0; p < 2; p++)
    bptr[p] = BT + (size_t)(n0 + rsub + p * 32) * Kd + gc * 8;
  char* ldsA = (char*)As + (t & 192) * 16;
  char* ldsB = (char*)Bs + (t & 192) * 16;

  int lane = t & 63;
  int wv = t >> 6;
  int wm = (wv >> 1) * 64, wn = (wv & 1) * 32;    // wave tile 64m x 32n
  int lr = lane & 15, lq = lane >> 4;
  int rx = lr & 7;                  // read-side row XOR key

  floatx4 acc[4][2];
#pragma unroll
  for (int i = 0; i < 4; i++)
#pragma unroll
    for (int j = 0; j < 2; j++) acc[i][j] = (floatx4){0.f, 0.f, 0.f, 0.f};

  for (int k0 = 0; k0 < Kd; k0 += 64) {
#pragma unroll
    for (int p = 0; p < 4; p++) gload16(aptr[p] + k0, ldsA + p * 4096);
#pragma unroll
    for (int p = 0; p < 2; p++) gload16(bptr[p] + k0, ldsB + p * 4096);
    __syncthreads();               // drains vmcnt(0): tile staged
#pragma unroll
    for (int kk = 0; kk < 2; kk++) {
      int ca = kk * 4 + lq;
      bhalf8 af[4], bf[2];
#pragma unroll
      for (int i = 0; i < 4; i++)
        af[i] = *(const bhalf8*)&As[(wm + i * 16 + lr) * 64 + ((ca ^ rx) * 8)];
#pragma unroll
      for (int j = 0; j < 2; j++)
        bf[j] = *(const bhalf8*)&Bs[(wn + j * 16 + lr) * 64 + ((ca ^ rx) * 8)];
#pragma unroll
      for (int i = 0; i < 4; i++)
#pragma unroll
        for (int j = 0; j < 2; j++)
          acc[i][j] = __builtin_amdgcn_mfma_f32_16x16x32_bf16(af[i], bf[j], acc[i][j], 0, 0, 0);
    }
    __syncthreads();               // protect buffer before next stage
  }

  // epilogue (block-uniform branch): ev -> weighted bf16 eout; sk -> gelu hidS
  if (is_ev) {
#pragma unroll
    for (int i = 0; i < 4; i++) {
#pragma unroll
      for (int j = 0; j < 2; j++) {
        int ncol = n0 + wn + j * 16 + lr;
        float bb = bias[ncol];
#pragma unroll
        for (int r = 0; r < 4; r++) {
          int prow = rbase + wm + i * 16 + lq * 4 + r;
          float w = permw[prow];
          float v = acc[i][j][r] + bb;
          eout[(size_t)prow * DM + ncol] = f2bf(w * v);
        }
      }
    }
  } else {
#pragma unroll
    for (int i = 0; i < 4; i++) {
#pragma unroll
      for (int j = 0; j < 2; j++) {
        int ncol = n0 + wn + j * 16 + lr;
        float bb = bias[ncol];
#pragma unroll
        for (int r = 0; r < 4; r++) {
          int mrow = rbase + wm + i * 16 + lq * 4 + r;
          float v = acc[i][j][r] + bb;
          hidS[(size_t)mrow * HD + ncol] = f2bf(gelu_tanh(v));
        }
      }
    }
  }
}

extern "C" void kernel_launch(void* const* d_in, const int* in_sizes, int n_in,
                              void* d_out, int out_size, void* d_ws, size_t ws_size,
                              hipStream_t stream) {
  const float* x        = (const float*)d_in[0];
  const float* gate_w   = (const float*)d_in[1];
  const float* keys_w   = (const float*)d_in[2];
  const float* keys_b   = (const float*)d_in[3];
  const float* values_w = (const float*)d_in[4];
  const float* values_b = (const float*)d_in[5];
  const float* sk_w     = (const float*)d_in[6];
  const float* sk_b     = (const float*)d_in[7];
  const float* sv_w     = (const float*)d_in[8];
  const float* sv_b     = (const float*)d_in[9];
  float* out = (float*)d_out;

  char* p = (char*)d_ws;
  unsigned short* xb   = (unsigned short*)p; p += (size_t)N_TOK * DM * 2;              // 16 MB
  unsigned short* wt   = (unsigned short*)p; p += (size_t)(NE + 2) * DM * HD * 2;      // 84 MB (10 slots)
  unsigned short* hid  = (unsigned short*)p; p += (size_t)(PERM_CAP + N_TOK) * HD * 2; // 209.7 MB
  unsigned short* eout = (unsigned short*)p; p += (size_t)PERM_CAP * DM * 2;           // 35.7 MB
  int*   idxb   = (int*)p;   p += NKTOT * 4;
  float* wbuf   = (float*)p; p += NKTOT * 4;
  int*   perm   = (int*)p;   p += PERM_CAP * 4;
  float* permw  = (float*)p; p += PERM_CAP * 4;
  int*   pos    = (int*)p;   p += NKTOT * 4;
  int*   counts = (int*)p;   p += NE * 4;
  int*   fill   = (int*)p;   p += NE * 4;
  int*   poff   = (int*)p;   p += NE * 4;
  float* usage  = (float*)p; p += NE * 4;
  float* zsum   = (float*)p; p += 16;
  int*   tileE  = (int*)p;   p += MAX_TILES * 4;
  int*   tileR  = (int*)p;   p += MAX_TILES * 4;
  int*   nTiles = (int*)p;   p += 16;

  float* lossOut = out + (size_t)N_TOK * DM;
  unsigned short* wt8  = wt + (size_t)NE * DM * HD;            // slot 8 (sk_w^T)
  unsigned short* wt9  = wt + (size_t)(NE + 1) * DM * HD;      // slot 9 (sv_w^T)
  unsigned short* hidS = hid + (size_t)PERM_CAP * HD;          // shared hidden rows

  // 1) init+cvt, router, scan, scatter
  init_cvt_kernel<<<N_TOK * DM / 4 / 256, 256, 0, stream>>>(
      x, xb, perm, permw, usage, zsum, counts, fill);
  router_kernel<<<N_TOK / RTOK_BLK, 256, 0, stream>>>(x, gate_w, idxb, wbuf, usage, zsum, counts);
  scan_kernel<<<1, 64, 0, stream>>>(counts, poff, tileE, tileR, nTiles, usage, zsum, lossOut);
  scatter_kernel<<<NKTOT / 256, 256, 0, stream>>>(idxb, wbuf, poff, fill, perm, permw, pos);

  // 2) keys transposes (9-slice): wt[0..7] = keys_w^T, wt[8] = sk_w^T
  transpose_cvt9_kernel<<<dim3(DM / 64, HD / 64, NE + 1), 256, 0, stream>>>(
      keys_w, sk_w, wt, wt8, DM, HD);

  // 3) expert keys: hid[expert rows] = gelu(x[perm] @ Wk_e + b_e)
  gemm_expert_keys<<<5120, 256, 0, stream>>>(             // 8 xcd * 20(m pad) * 32 n
      xb, wt, keys_b, hid, DM, HD, perm, tileE, tileR, nTiles);

  // 4) values+sv transposes (9-slice; wt8 untouched -> sk branch safe),
  //    then merged ev+sk (BN=64, 6272 blocks)
  transpose_cvt9_kernel<<<dim3(HD / 64, DM / 64, NE + 1), 256, 0, stream>>>(
      values_w, sv_w, wt, wt9, HD, DM);
  gemm_ev_sk<<<EV2_BLOCKS + SK2_BLOCKS, 256, 0, stream>>>(
      hid, wt, values_b, eout, xb, wt8, sk_b, hidS,
      permw, tileE, tileR, nTiles);

  // 5) shared values: 1024 blocks exact (BN=64 body), reads wt9
  gemm_shared_values<<<1024, 256, 0, stream>>>(hidS, wt9, sv_b, out);

  // 6) out += top-2 expert contributions
  combine_kernel<<<N_TOK, 128, 0, stream>>>(out, eout, pos);
}

// Round 17
// 876.706 us; speedup vs baseline: 1.1724x; 1.0763x over previous
//
#include <hip/hip_runtime.h>
#include <hip/hip_bf16.h>

// MoE top-2-of-8 FFN + shared expert + router losses, MI355X gfx950.
// FINAL (R21 = R15 verbatim, best measured 886.8us).
// Session ledger:
//   R5: router/scatter atomic de-serialization (-300us).
//   R8: m97-canonical 128^2 single-buffer GEMM, 4 blocks/CU (inter-block TLP
//       hides stage drain; ~1300 TF chip packing rate).
//   R9/R10: launch_bounds(256,5) silently spills (body needs 128 unified
//       regs = 64 VGPR + 64 AGPR; 5 waves/SIMD allows 102). Never exceed.
//   R11/R12/R20: BN=64 / BM=256 tile variants all lose: item time tracks
//       staged bytes (AI), so only full-AI 128^2 items hit the packing rate.
//   R13/R18: slot-count quantization fixes without AI preservation are null.
//   R15: ev+sk backfill merge, ONE code path (233us; pigeonhole floor 210
//       since 1088 x 105us items > 1024 slots). WIN.
//   R14/R16/R19: merge traps (per-instantiation LDS/VGPR union; streaming
//       transpose co-scheduled with gather-GEMM destroys its L2 reuse).
//   R17: dispatch launch gaps measured ~0 (13 -> 11 dispatches neutral).

#define N_TOK 8192
#define DM    1024
#define HD    4096
#define NE    8
#define NKTOT 16384            // N_TOK * 2
#define PERM_CAP 17408         // NKTOT + NE*128 (segment padding)
#define MAX_TILES 136          // sum ceil(T_e/128) <= NKTOT/128 + NE
#define BAND 17                // MAX_TILES / 8 xcds
#define EV_BLOCKS 1088         // 8 xcd * 17 m * 8 n
#define RTOK_BLK 16            // router tokens per block

typedef __attribute__((ext_vector_type(8))) short bhalf8;
typedef __attribute__((ext_vector_type(8))) unsigned short ushort8v;
typedef __attribute__((ext_vector_type(4))) float floatx4;

__device__ __forceinline__ unsigned short f2bf(float f) {
  union { float f; unsigned int u; } v; v.f = f;
  unsigned int u = v.u;
  return (unsigned short)((u + 0x7fffu + ((u >> 16) & 1u)) >> 16);  // RNE
}

__device__ __forceinline__ float bf2f(unsigned short h) {
  union { unsigned int u; float f; } v; v.u = ((unsigned int)h) << 16;
  return v.f;
}

__device__ __forceinline__ float gelu_tanh(float h) {
  // jax.nn.gelu default (approximate=True)
  float u = 0.7978845608028654f * (h + 0.044715f * h * h * h);
  float t = 1.0f - 2.0f / (1.0f + __expf(2.0f * u));   // tanh(u)
  return 0.5f * h * (1.0f + t);
}

// global -> LDS direct DMA, 16B/lane. LDS dest is wave-uniform base + lane*16.
__device__ __forceinline__ void gload16(const unsigned short* g, void* l) {
  __builtin_amdgcn_global_load_lds(
      (const __attribute__((address_space(1))) void*)g,
      (__attribute__((address_space(3))) void*)l, 16, 0, 0);
}

// ---------------- init (ws is poisoned 0xAA each call) ----------------
__global__ void init_kernel(int* perm, float* permw, float* usage, float* zsum,
                            int* counts, int* fill) {
  int i = blockIdx.x * 256 + threadIdx.x;
  if (i < PERM_CAP) { perm[i] = 0; permw[i] = 0.0f; }
  if (i < NE) { usage[i] = 0.0f; counts[i] = 0; fill[i] = 0; }
  if (i == 0) zsum[0] = 0.0f;
}

// ---------------- x fp32 -> bf16 ----------------
__global__ void cvt_x_kernel(const float* __restrict__ x, unsigned short* __restrict__ xb) {
  size_t i = (size_t)(blockIdx.x * 256 + threadIdx.x) * 4;
  float4 v = *(const float4*)(x + i);
  ushort4 o;
  o.x = f2bf(v.x); o.y = f2bf(v.y); o.z = f2bf(v.z); o.w = f2bf(v.w);
  *(ushort4*)(xb + i) = o;
}

// ---------------- router: logits, top-2 softmax, aux-loss partials ----------------
__global__ void router_kernel(const float* __restrict__ x, const float* __restrict__ gw,
                              int* __restrict__ idxb, float* __restrict__ wbuf,
                              float* __restrict__ usage, float* __restrict__ zsum,
                              int* __restrict__ counts) {
  __shared__ float s_use[NE];
  __shared__ int   s_cnt[NE];
  __shared__ float s_z;
  int t = threadIdx.x;
  if (t < NE) { s_use[t] = 0.0f; s_cnt[t] = 0; }
  if (t == 0) s_z = 0.0f;
  __syncthreads();

  int wave = t >> 6;
  int lane = t & 63;

  float luse[NE]; int lcnt[NE];
#pragma unroll
  for (int e = 0; e < NE; e++) { luse[e] = 0.0f; lcnt[e] = 0; }
  float lz = 0.0f;

#pragma unroll
  for (int i = 0; i < 4; i++) {
    int n = blockIdx.x * RTOK_BLK + wave * 4 + i;
    const float* xr = x + (size_t)n * DM;
    float acc[NE];
#pragma unroll
    for (int e = 0; e < NE; e++) acc[e] = 0.0f;
    for (int d = lane; d < DM; d += 64) {
      float xv = xr[d];
      const float* g = gw + (size_t)d * NE;
#pragma unroll
      for (int e = 0; e < NE; e++) acc[e] += xv * g[e];
    }
#pragma unroll
    for (int e = 0; e < NE; e++) {
#pragma unroll
      for (int off = 32; off > 0; off >>= 1) acc[e] += __shfl_xor(acc[e], off);
    }
    if (lane == 0) {
      float m1 = acc[0]; int i1 = 0;
#pragma unroll
      for (int e = 1; e < NE; e++) if (acc[e] > m1) { m1 = acc[e]; i1 = e; }
      float m2 = -3.0e38f; int i2 = 0;
#pragma unroll
      for (int e = 0; e < NE; e++) if (e != i1 && acc[e] > m2) { m2 = acc[e]; i2 = e; }
      float e1 = __expf(m2 - m1);
      float w1 = 1.0f / (1.0f + e1);
      float w2 = e1 / (1.0f + e1);
      float s = 0.0f;
#pragma unroll
      for (int e = 0; e < NE; e++) s += __expf(acc[e] - m1);
      float lse = m1 + __logf(s);
      idxb[n * 2 + 0] = i1; idxb[n * 2 + 1] = i2;
      wbuf[n * 2 + 0] = w1; wbuf[n * 2 + 1] = w2;
      luse[i1] += w1; luse[i2] += w2;
      lcnt[i1]++;     lcnt[i2]++;
      lz += lse * lse;
    }
  }

  if (lane == 0) {
#pragma unroll
    for (int e = 0; e < NE; e++) {
      atomicAdd(&s_use[e], luse[e]);
      atomicAdd(&s_cnt[e], lcnt[e]);
    }
    atomicAdd(&s_z, lz);
  }
  __syncthreads();
  if (t < NE) {
    atomicAdd(&usage[t], s_use[t]);
    atomicAdd(&counts[t], s_cnt[t]);
  }
  if (t == 0) atomicAdd(zsum, s_z);
}

// ---------------- scan: padded segment offsets, tile table, router loss ----------------
__global__ void scan_kernel(const int* __restrict__ counts, int* __restrict__ poff,
                            int* __restrict__ tileE, int* __restrict__ tileR,
                            int* __restrict__ nTiles,
                            const float* __restrict__ usage, const float* __restrict__ zsum,
                            float* __restrict__ lossOut) {
  if (threadIdx.x == 0 && blockIdx.x == 0) {
    int run = 0, nt = 0;
    for (int e = 0; e < NE; e++) {
      poff[e] = run;
      int t = (counts[e] + 127) >> 7;
      for (int i = 0; i < t; i++) { tileE[nt] = e; tileR[nt] = run + i * 128; nt++; }
      run += t << 7;
    }
    *nTiles = nt;
    float mean = 0.0f;
    for (int e = 0; e < NE; e++) mean += usage[e];
    mean *= (1.0f / NE);
    float var = 0.0f;
    for (int e = 0; e < NE; e++) { float d = usage[e] - mean; var += d * d; }
    var *= (1.0f / NE);
    float bal = sqrtf(var) / mean * 0.01f;
    float z = (zsum[0] / (float)N_TOK) * 0.001f;
    lossOut[0] = bal + z;
  }
}

// ---------------- scatter tokens into per-expert segments ----------------
__global__ void scatter_kernel(const int* __restrict__ idxb, const float* __restrict__ wbuf,
                               const int* __restrict__ poff, int* __restrict__ fill,
                               int* __restrict__ perm, float* __restrict__ permw,
                               int* __restrict__ pos) {
  __shared__ int lcnt[NE];
  __shared__ int lbase[NE];
  int t = threadIdx.x;
  if (t < NE) lcnt[t] = 0;
  __syncthreads();
  int i = blockIdx.x * 256 + t;          // grid sized exactly: i < NKTOT
  int e = idxb[i];
  int r = atomicAdd(&lcnt[e], 1);        // LDS rank within block
  __syncthreads();
  if (t < NE) lbase[t] = atomicAdd(&fill[t], lcnt[t]);
  __syncthreads();
  int p = poff[e] + lbase[e] + r;
  perm[p] = i >> 1;
  permw[p] = wbuf[i];
  pos[i] = p;
}

// ---------------- transpose+convert: fp32 [R][C] -> bf16 [C][R] ----------------
// dst writes vectorized: each lane stores ushort8 (16B). LDS read stride 65
// words -> 2-way bank aliasing only (free).
__device__ __forceinline__ void tr_body(const float* __restrict__ src,
                                        unsigned short* __restrict__ dst, int R, int C) {
  __shared__ float tile[64][65];
  int r0 = blockIdx.x * 64, c0 = blockIdx.y * 64;
  int c = threadIdx.x & 63, r = threadIdx.x >> 6;
#pragma unroll
  for (int i = 0; i < 16; i++)
    tile[r + i * 4][c] = src[(size_t)(r0 + r + i * 4) * C + c0 + c];
  __syncthreads();
  int u = threadIdx.x & 7;        // dst 8-col group (src row group)
  int ow = threadIdx.x >> 3;      // 0..31: dst row offset base
#pragma unroll
  for (int it = 0; it < 2; it++) {
    int oc = ow + it * 32;        // src col -> dst row offset
    ushort8v o;
#pragma unroll
    for (int j = 0; j < 8; j++) o[j] = f2bf(tile[u * 8 + j][oc]);
    *(ushort8v*)&dst[(size_t)(c0 + oc) * R + r0 + u * 8] = o;
  }
}

__global__ void transpose_cvt_kernel(const float* __restrict__ src,
                                     unsigned short* __restrict__ dst, int R, int C) {
  size_t bo = (size_t)blockIdx.z * R * C;
  tr_body(src + bo, dst + bo, R, C);
}

// ---------------- combine: out[t] += eout[pos0[t]] + eout[pos1[t]] ----------------
__global__ void combine_kernel(float* __restrict__ out,
                               const unsigned short* __restrict__ eout,
                               const int* __restrict__ pos) {
  int t = blockIdx.x;
  int d = threadIdx.x * 8;
  int p0 = pos[t * 2], p1 = pos[t * 2 + 1];
  float* o = out + (size_t)t * DM + d;
  const unsigned short* e0 = eout + (size_t)p0 * DM + d;
  const unsigned short* e1 = eout + (size_t)p1 * DM + d;
  float4 a = *(const float4*)(o);
  float4 b = *(const float4*)(o + 4);
  ushort4 u0a = *(const ushort4*)(e0), u0b = *(const ushort4*)(e0 + 4);
  ushort4 u1a = *(const ushort4*)(e1), u1b = *(const ushort4*)(e1 + 4);
  a.x += bf2f(u0a.x) + bf2f(u1a.x);
  a.y += bf2f(u0a.y) + bf2f(u1a.y);
  a.z += bf2f(u0a.z) + bf2f(u1a.z);
  a.w += bf2f(u0a.w) + bf2f(u1a.w);
  b.x += bf2f(u0b.x) + bf2f(u1b.x);
  b.y += bf2f(u0b.y) + bf2f(u1b.y);
  b.z += bf2f(u0b.z) + bf2f(u1b.z);
  b.w += bf2f(u0b.w) + bf2f(u1b.w);
  *(float4*)(o) = a;
  *(float4*)(o + 4) = b;
}

// ---------------- 128x128xBK64 bf16 MFMA GEMM, m97-canonical single buffer ----------------
// 256 threads = 4 waves (2x2 of 64x64 wave tiles). LDS 32KB, 4 blocks/CU
// (64 VGPR + 64 AGPR = 128 unified = the 4/CU cliff; no extra live regs).
// MODE 1 = sv (dense rows, f32 out)   MODE 2 = ek (perm rows, gelu bf16 out)
template<int MODE>
__device__ __forceinline__ void gemm_body(
    int id,
    const unsigned short* __restrict__ A,
    const unsigned short* __restrict__ BT,
    const float* __restrict__ bias,
    float* __restrict__ outF,
    unsigned short* __restrict__ outH,
    int Kd, int Nd,
    const int* __restrict__ perm,
    const int* __restrict__ tileE,
    const int* __restrict__ tileR,
    const int* __restrict__ nTiles) {
  __shared__ __align__(16) unsigned short As[128 * 64];
  __shared__ __align__(16) unsigned short Bs[128 * 64];

  int xcd = id & 7, q = id >> 3;
  int mt, ntile;
  if (MODE == 1) {              // band 8m, n-fastest
    ntile = q & 7;
    mt = xcd * 8 + (q >> 3);
  } else {                      // band 17m, supertile 4m x 8n
    int n_in = q & 7, m_in = (q >> 3) & 3, ng = (q >> 5) & 3, mg = q >> 7;
    int mband = mg * 4 + m_in;
    if (mband >= BAND) return;
    mt = xcd * BAND + mband;
    ntile = ng * 8 + n_in;
  }

  int n0 = ntile * 128;
  int prow0 = 0, m0 = 0;
  if (MODE == 2) {
    if (mt >= *nTiles) return;
    int e = tileE[mt];
    prow0 = tileR[mt];
    BT += (size_t)e * Kd * Nd;
    bias += (size_t)e * Nd;
  } else {
    m0 = mt * 128;
  }

  int t = threadIdx.x;
  int rsub = t >> 3;               // 0..31: row within 32-row staging slab
  int gc = (t & 7) ^ (rsub & 7);   // swizzled global 16B-chunk index
  const unsigned short* aptr[4];
  const unsigned short* bptr[4];
#pragma unroll
  for (int p = 0; p < 4; p++) {
    int r = rsub + p * 32;
    size_t grow;
    if (MODE == 2) grow = (size_t)perm[prow0 + r];
    else           grow = (size_t)(m0 + r);
    aptr[p] = A + grow * Kd + gc * 8;
    bptr[p] = BT + (size_t)(n0 + r) * Kd + gc * 8;
  }
  char* ldsA = (char*)As + (t & 192) * 16;
  char* ldsB = (char*)Bs + (t & 192) * 16;

  int lane = t & 63;
  int wv = t >> 6;
  int wm = (wv >> 1) * 64, wn = (wv & 1) * 64;
  int lr = lane & 15, lq = lane >> 4;
  int rx = lr & 7;                  // read-side row XOR key

  floatx4 acc[4][4];
#pragma unroll
  for (int i = 0; i < 4; i++)
#pragma unroll
    for (int j = 0; j < 4; j++) acc[i][j] = (floatx4){0.f, 0.f, 0.f, 0.f};

  for (int k0 = 0; k0 < Kd; k0 += 64) {
#pragma unroll
    for (int p = 0; p < 4; p++) {
      gload16(aptr[p] + k0, ldsA + p * 4096);
      gload16(bptr[p] + k0, ldsB + p * 4096);
    }
    __syncthreads();               // drains vmcnt(0): tile staged
#pragma unroll
    for (int kk = 0; kk < 2; kk++) {       // two 16x16x32 k-steps
      int ca = kk * 4 + lq;                // global chunk for this frag
      bhalf8 af[4], bf[4];
#pragma unroll
      for (int i = 0; i < 4; i++) {
        af[i] = *(const bhalf8*)&As[(wm + i * 16 + lr) * 64 + ((ca ^ rx) * 8)];
        bf[i] = *(const bhalf8*)&Bs[(wn + i * 16 + lr) * 64 + ((ca ^ rx) * 8)];
      }
#pragma unroll
      for (int mtile = 0; mtile < 4; mtile++)
#pragma unroll
        for (int ntl = 0; ntl < 4; ntl++)
          acc[mtile][ntl] = __builtin_amdgcn_mfma_f32_16x16x32_bf16(af[mtile], bf[ntl], acc[mtile][ntl], 0, 0, 0);
    }
    __syncthreads();               // protect buffer before next stage
  }

  // epilogue: D[row=(lane>>4)*4+reg][col=lane&15]
#pragma unroll
  for (int mtile = 0; mtile < 4; mtile++) {
#pragma unroll
    for (int ntl = 0; ntl < 4; ntl++) {
      int ncol = n0 + wn + ntl * 16 + lr;
      float bb = bias[ncol];
#pragma unroll
      for (int r = 0; r < 4; r++) {
        int mrow = wm + mtile * 16 + lq * 4 + r;    // local row 0..127
        float v = acc[mtile][ntl][r] + bb;
        if (MODE == 1) {
          outF[(size_t)(m0 + mrow) * Nd + ncol] = v;
        } else {
          outH[(size_t)(prow0 + mrow) * Nd + ncol] = f2bf(gelu_tanh(v));
        }
      }
    }
  }
}

__global__ __launch_bounds__(256, 4) void gemm_expert_keys(
    const unsigned short* A, const unsigned short* BT, const float* bias,
    float* outF, unsigned short* outH, int Kd, int Nd,
    const int* perm, const int* tE, const int* tR, const int* nT) {
  gemm_body<2>(blockIdx.x, A, BT, bias, outF, outH, Kd, Nd, perm, tE, tR, nT);
}
__global__ __launch_bounds__(256, 4) void gemm_shared_values(
    const unsigned short* A, const unsigned short* BT, const float* bias,
    float* outF, unsigned short* outH, int Kd, int Nd,
    const int* perm, const int* tE, const int* tR, const int* nT) {
  gemm_body<1>(blockIdx.x, A, BT, bias, outF, outH, Kd, Nd, perm, tE, tR, nT);
}

// ---------------- merged ev+sk: ONE code path, runtime block-uniform selects ----------------
// ids [0,1088) = expert_values (K=4096 long items, launch first);
// ids [1088,3136) = shared_keys (K=1024 short items, backfill the tail).
// Both branches direct-row; staging + K-loop is the same instruction stream;
// only scalar setup and the epilogue differ. Single 32KB pair -> 4 blocks/CU.
__global__ __launch_bounds__(256, 4) void gemm_ev_sk(
    const unsigned short* __restrict__ hid, const unsigned short* __restrict__ wtV,
    const float* __restrict__ values_b, unsigned short* __restrict__ eout,
    const unsigned short* __restrict__ xb, const unsigned short* __restrict__ wtK8,
    const float* __restrict__ sk_b, unsigned short* __restrict__ hidS,
    const float* __restrict__ permw,
    const int* __restrict__ tileE, const int* __restrict__ tileR,
    const int* __restrict__ nTiles) {
  __shared__ __align__(16) unsigned short As[128 * 64];
  __shared__ __align__(16) unsigned short Bs[128 * 64];

  int id = blockIdx.x;
  bool is_ev = id < EV_BLOCKS;

  int Kd, rbase, n0;
  const unsigned short* A;
  const unsigned short* BT;
  const float* bias;
  if (is_ev) {                       // band 17m, n-fastest per m
    int xcd = id & 7, q = id >> 3;
    int mt = xcd * BAND + (q >> 3);
    if (mt >= *nTiles) return;
    int e = tileE[mt];
    rbase = tileR[mt];
    n0 = (q & 7) * 128;
    Kd = HD;
    A = hid;
    BT = wtV + (size_t)e * HD * DM;
    bias = values_b + (size_t)e * DM;
  } else {                           // sk: band 8m, m-fastest
    int id2 = id - EV_BLOCKS;
    int xcd = id2 & 7, q = id2 >> 3;
    int mt = xcd * 8 + (q & 7);
    rbase = mt * 128;
    n0 = (q >> 3) * 128;
    Kd = DM;
    A = xb;
    BT = wtK8;
    bias = sk_b;
  }

  int t = threadIdx.x;
  int rsub = t >> 3;               // 0..31: row within 32-row staging slab
  int gc = (t & 7) ^ (rsub & 7);   // swizzled global 16B-chunk index
  const unsigned short* aptr[4];
  const unsigned short* bptr[4];
#pragma unroll
  for (int p = 0; p < 4; p++) {
    int r = rsub + p * 32;
    aptr[p] = A + (size_t)(rbase + r) * Kd + gc * 8;
    bptr[p] = BT + (size_t)(n0 + r) * Kd + gc * 8;
  }
  char* ldsA = (char*)As + (t & 192) * 16;
  char* ldsB = (char*)Bs + (t & 192) * 16;

  int lane = t & 63;
  int wv = t >> 6;
  int wm = (wv >> 1) * 64, wn = (wv & 1) * 64;
  int lr = lane & 15, lq = lane >> 4;
  int rx = lr & 7;                  // read-side row XOR key

  floatx4 acc[4][4];
#pragma unroll
  for (int i = 0; i < 4; i++)
#pragma unroll
    for (int j = 0; j < 4; j++) acc[i][j] = (floatx4){0.f, 0.f, 0.f, 0.f};

  for (int k0 = 0; k0 < Kd; k0 += 64) {
#pragma unroll
    for (int p = 0; p < 4; p++) {
      gload16(aptr[p] + k0, ldsA + p * 4096);
      gload16(bptr[p] + k0, ldsB + p * 4096);
    }
    __syncthreads();
#pragma unroll
    for (int kk = 0; kk < 2; kk++) {
      int ca = kk * 4 + lq;
      bhalf8 af[4], bf[4];
#pragma unroll
      for (int i = 0; i < 4; i++) {
        af[i] = *(const bhalf8*)&As[(wm + i * 16 + lr) * 64 + ((ca ^ rx) * 8)];
        bf[i] = *(const bhalf8*)&Bs[(wn + i * 16 + lr) * 64 + ((ca ^ rx) * 8)];
      }
#pragma unroll
      for (int mtile = 0; mtile < 4; mtile++)
#pragma unroll
        for (int ntl = 0; ntl < 4; ntl++)
          acc[mtile][ntl] = __builtin_amdgcn_mfma_f32_16x16x32_bf16(af[mtile], bf[ntl], acc[mtile][ntl], 0, 0, 0);
    }
    __syncthreads();
  }

  // epilogue (block-uniform branch)
  if (is_ev) {
#pragma unroll
    for (int mtile = 0; mtile < 4; mtile++) {
#pragma unroll
      for (int ntl = 0; ntl < 4; ntl++) {
        int ncol = n0 + wn + ntl * 16 + lr;
        float bb = bias[ncol];
#pragma unroll
        for (int r = 0; r < 4; r++) {
          int prow = rbase + wm + mtile * 16 + lq * 4 + r;
          float w = permw[prow];
          float v = acc[mtile][ntl][r] + bb;
          eout[(size_t)prow * DM + ncol] = f2bf(w * v);
        }
      }
    }
  } else {
#pragma unroll
    for (int mtile = 0; mtile < 4; mtile++) {
#pragma unroll
      for (int ntl = 0; ntl < 4; ntl++) {
        int ncol = n0 + wn + ntl * 16 + lr;
        float bb = bias[ncol];
#pragma unroll
        for (int r = 0; r < 4; r++) {
          int mrow = rbase + wm + mtile * 16 + lq * 4 + r;
          float v = acc[mtile][ntl][r] + bb;
          hidS[(size_t)mrow * HD + ncol] = f2bf(gelu_tanh(v));
        }
      }
    }
  }
}

extern "C" void kernel_launch(void* const* d_in, const int* in_sizes, int n_in,
                              void* d_out, int out_size, void* d_ws, size_t ws_size,
                              hipStream_t stream) {
  const float* x        = (const float*)d_in[0];
  const float* gate_w   = (const float*)d_in[1];
  const float* keys_w   = (const float*)d_in[2];
  const float* keys_b   = (const float*)d_in[3];
  const float* values_w = (const float*)d_in[4];
  const float* values_b = (const float*)d_in[5];
  const float* sk_w     = (const float*)d_in[6];
  const float* sk_b     = (const float*)d_in[7];
  const float* sv_w     = (const float*)d_in[8];
  const float* sv_b     = (const float*)d_in[9];
  float* out = (float*)d_out;

  char* p = (char*)d_ws;
  unsigned short* xb   = (unsigned short*)p; p += (size_t)N_TOK * DM * 2;              // 16 MB
  unsigned short* wt   = (unsigned short*)p; p += (size_t)(NE + 1) * DM * HD * 2;      // 75.5 MB (9 slots)
  unsigned short* hid  = (unsigned short*)p; p += (size_t)(PERM_CAP + N_TOK) * HD * 2; // 209.7 MB
  unsigned short* eout = (unsigned short*)p; p += (size_t)PERM_CAP * DM * 2;           // 35.7 MB
  int*   idxb   = (int*)p;   p += NKTOT * 4;
  float* wbuf   = (float*)p; p += NKTOT * 4;
  int*   perm   = (int*)p;   p += PERM_CAP * 4;
  float* permw  = (float*)p; p += PERM_CAP * 4;
  int*   pos    = (int*)p;   p += NKTOT * 4;
  int*   counts = (int*)p;   p += NE * 4;
  int*   fill   = (int*)p;   p += NE * 4;
  int*   poff   = (int*)p;   p += NE * 4;
  float* usage  = (float*)p; p += NE * 4;
  float* zsum   = (float*)p; p += 16;
  int*   tileE  = (int*)p;   p += MAX_TILES * 4;
  int*   tileR  = (int*)p;   p += MAX_TILES * 4;
  int*   nTiles = (int*)p;   p += 16;

  float* lossOut = out + (size_t)N_TOK * DM;
  unsigned short* wtK8 = wt + (size_t)NE * DM * HD;            // sk_w^T slot
  unsigned short* hidS = hid + (size_t)PERM_CAP * HD;          // shared hidden rows

  // 1) init + convert + router + scan + scatter
  init_kernel<<<(PERM_CAP + 255) / 256, 256, 0, stream>>>(perm, permw, usage, zsum, counts, fill);
  cvt_x_kernel<<<(N_TOK * DM / 4 + 255) / 256, 256, 0, stream>>>(x, xb);
  router_kernel<<<N_TOK / RTOK_BLK, 256, 0, stream>>>(x, gate_w, idxb, wbuf, usage, zsum, counts);
  scan_kernel<<<1, 64, 0, stream>>>(counts, poff, tileE, tileR, nTiles, usage, zsum, lossOut);
  scatter_kernel<<<NKTOT / 256, 256, 0, stream>>>(idxb, wbuf, poff, fill, perm, permw, pos);

  // 2) keys transposes: wt[0..7] = keys_w^T, wt[8] = sk_w^T
  transpose_cvt_kernel<<<dim3(DM / 64, HD / 64, NE), 256, 0, stream>>>(keys_w, wt, DM, HD);
  transpose_cvt_kernel<<<dim3(DM / 64, HD / 64, 1), 256, 0, stream>>>(sk_w, wtK8, DM, HD);

  // 3) expert keys: hid[expert rows] = gelu(x[perm] @ Wk_e + b_e)
  gemm_expert_keys<<<5120, 256, 0, stream>>>(             // 8 xcd * 20(m pad) * 32 n
      xb, wt, keys_b, nullptr, hid, DM, HD, perm, tileE, tileR, nTiles);

  // 4) values transpose (overwrites keys slots; ek done), then merged ev+sk
  transpose_cvt_kernel<<<dim3(HD / 64, DM / 64, NE), 256, 0, stream>>>(values_w, wt, HD, DM);
  gemm_ev_sk<<<EV_BLOCKS + 2048, 256, 0, stream>>>(
      hid, wt, values_b, eout, xb, wtK8, sk_b, hidS,
      permw, tileE, tileR, nTiles);

  // 5) sv transpose into wt[8] (sk done), then shared values
  transpose_cvt_kernel<<<dim3(HD / 64, DM / 64, 1), 256, 0, stream>>>(sv_w, wtK8, HD, DM);
  gemm_shared_values<<<512, 256, 0, stream>>>(            // 8 xcd * 8 m * 8 n
      hidS, wtK8, sv_b, out, nullptr, HD, DM, perm, tileE, tileR, nTiles);

  // 6) out += top-2 expert contributions
  combine_kernel<<<N_TOK, 128, 0, stream>>>(out, eout, pos);
}